// Round 7
// baseline (328.748 us; speedup 1.0000x reference)
//
#include <hip/hip_runtime.h>

// ComplexMultiHeadAttention: B=2, N=2048, D=1024, H=16, hd=64
// Fast path (ws >= 84MB): [cvt_prepass f32->bf16] -> [qkv_gemm_dma] -> [attn_fwd]
//                         -> [out_gemm_dma] ; obuf aliases xbf (dead after qkv).
// Fallback (small ws): legacy GEMMs + same attn.

#define DIM_   1024
#define HEADS_ 16
#define HD_    64
#define BB_    2
#define NN_    2048
#define MTOT_  (BB_*NN_)      // 4096
#define SCALE_ 0.125f
// Q is pre-scaled by SCALE_*log2(e) in the qkv GEMM epilogue, so attn's
// softmax is pv = exp2(|S|) directly.
#define QSCALE_ 0.1803368801111243f   // 0.125 * 1.44269504

typedef __bf16 bf16;
typedef __bf16 bf16x8 __attribute__((ext_vector_type(8)));
typedef short  s16x8  __attribute__((ext_vector_type(8)));
typedef float  fx4    __attribute__((ext_vector_type(4)));

__device__ __forceinline__ bf16x8 neg8(bf16x8 v) {
    s16x8 s;
    __builtin_memcpy(&s, &v, sizeof(s));
    s ^= (short)0x8000;
    bf16x8 r;
    __builtin_memcpy(&r, &s, sizeof(r));
    return r;
}

__device__ __forceinline__ void gl_lds16(const void* g, void* l) {
    __builtin_amdgcn_global_load_lds(
        (const __attribute__((address_space(1))) unsigned int*)g,
        (__attribute__((address_space(3))) unsigned int*)l, 16, 0, 0);
}

// Counted-vmcnt pipeline barriers (attn: 2 DMAs/wave/tile; GEMM: 3).
#define PIPE_SYNC() asm volatile("s_waitcnt vmcnt(2)\n\ts_barrier" ::: "memory")
#define PIPE_G3()   asm volatile("s_waitcnt vmcnt(3)\n\ts_barrier" ::: "memory")
#define FULL_SYNC() asm volatile("s_waitcnt vmcnt(0)\n\ts_barrier" ::: "memory")

// ---------------------------------------------------------------------------
// Prepass: f32 -> bf16 for x (8.39M), Wqkv (6.29M), Wout (2.1M). 8192 blocks.
// ---------------------------------------------------------------------------
__global__ __launch_bounds__(256) void cvt_prepass(
    const float* __restrict__ xr, const float* __restrict__ xi,
    const float* __restrict__ wqr, const float* __restrict__ wqi,
    const float* __restrict__ wor, const float* __restrict__ woi,
    bf16* __restrict__ xbf, bf16* __restrict__ wqkv, bf16* __restrict__ wout)
{
    const int bid = blockIdx.x;
    const float* src; bf16* dst; int rel;
    if      (bid < 2048) { src = xr;  dst = xbf;           rel = bid; }
    else if (bid < 4096) { src = xi;  dst = xbf + 4194304; rel = bid - 2048; }
    else if (bid < 5632) { src = wqr; dst = wqkv;          rel = bid - 4096; }
    else if (bid < 7168) { src = wqi; dst = wqkv + 3145728; rel = bid - 5632; }
    else if (bid < 7680) { src = wor; dst = wout;          rel = bid - 7168; }
    else                 { src = woi; dst = wout + 1048576; rel = bid - 7680; }
    size_t base = (size_t)rel * 2048 + (size_t)threadIdx.x * 8;
    fx4 a = *(const fx4*)(src + base);
    fx4 b = *(const fx4*)(src + base + 4);
    bf16x8 o;
#pragma unroll
    for (int j = 0; j < 4; ++j) { o[j] = (bf16)a[j]; o[j+4] = (bf16)b[j]; }
    *(bf16x8*)(dst + base) = o;
}

// ---------------------------------------------------------------------------
// Pipelined GEMM core v3: C[m,c] = A[m,:].B[c,:], A/B bf16 row-major [..][1024].
// 256x128 tile, BK=32, 8 waves (512 thr), each wave owns a 64x64 sub-tile
// (wm=(w>>1)*64, wn=(w&1)*64). TRIPLE-buffered distance-2 prefetch via
// global_load_lds, counted vmcnt(3) (3 DMAs/wave/step: A x2, B x1).
// 72KB LDS -> 2 blocks/CU = 16 waves/CU (R6 was 12). B panel re-fetched by
// 16 m-blocks (was 32) -> half the weight traffic.
// LDS chunk swizzle (row mod 16 based, same both sides): chunk ^ (r&3)^((r>>2)&3).
// XCD-aware bijective block swizzle (total blocks % 8 == 0).
// ---------------------------------------------------------------------------
#define GEMM_CORE_P(Aptr, Bptr, NWGX, NWGY)                                    \
    __shared__ __align__(16) bf16 LS[3*12288];   /* per buf: A 8192 | B 4096 */\
    const int tid  = threadIdx.x;                                              \
    const int w    = tid >> 6, lane = tid & 63;                                \
    const int quad = lane >> 4, lc = lane & 15;                                \
    const int wm   = (w >> 1) * 64, wn = (w & 1) * 64;                         \
    const int rl   = lane >> 2, cl = lane & 3;                                 \
    const int swc  = cl ^ ((rl & 3) ^ ((rl >> 2) & 3));                        \
    const int rsw  = (quad ^ ((lc & 3) ^ ((lc >> 2) & 3))) * 8;                \
    int flat = blockIdx.y * (NWGX) + blockIdx.x;                               \
    flat = (flat & 7) * (((NWGX) * (NWGY)) / 8) + (flat >> 3);                 \
    const int m0 = (flat / (NWGX)) * 256;                                      \
    const int n0 = (flat % (NWGX)) * 128;                                      \
    const fx4 fzero = {0.f, 0.f, 0.f, 0.f};                                    \
    fx4 acc[4][4];                                                             \
    _Pragma("unroll")                                                          \
    for (int mi = 0; mi < 4; ++mi)                                             \
        _Pragma("unroll")                                                      \
        for (int ni = 0; ni < 4; ++ni) acc[mi][ni] = fzero;                    \
    const bf16* aSrc = Aptr + (size_t)(m0 + w*32 + rl)*DIM_ + swc*8;           \
    const bf16* bSrc = Bptr + (size_t)(n0 + w*16 + rl)*DIM_ + swc*8;           \
    auto STG = [&](int kk, int bb) {                                           \
        gl_lds16(aSrc + kk,           LS + bb + w*1024);                       \
        gl_lds16(aSrc + kk + 16*DIM_, LS + bb + w*1024 + 512);                 \
        gl_lds16(bSrc + kk,           LS + bb + 8192 + w*512);                 \
    };                                                                         \
    STG(0, 0);                                                                 \
    STG(32, 12288);                                                            \
    PIPE_G3();                                                                 \
    {                                                                          \
        int b0 = 0, b1 = 12288, b2 = 24576;                                    \
        for (int s = 0; s < 32; ++s) {                                         \
            if (s < 30) STG((s + 2) * 32, b2);                                 \
            bf16x8 af[4], bfr[4];                                              \
            _Pragma("unroll")                                                  \
            for (int mi = 0; mi < 4; ++mi)                                     \
                af[mi] = *(bf16x8*)&LS[b0 + (wm + mi*16 + lc)*32 + rsw];       \
            _Pragma("unroll")                                                  \
            for (int ni = 0; ni < 4; ++ni)                                     \
                bfr[ni] = *(bf16x8*)&LS[b0 + 8192 + (wn + ni*16 + lc)*32 + rsw]; \
            _Pragma("unroll")                                                  \
            for (int mi = 0; mi < 4; ++mi)                                     \
                _Pragma("unroll")                                              \
                for (int ni = 0; ni < 4; ++ni)                                 \
                    acc[mi][ni] = __builtin_amdgcn_mfma_f32_16x16x32_bf16(     \
                        af[mi], bfr[ni], acc[mi][ni], 0, 0, 0);                \
            if (s == 30) FULL_SYNC();                                          \
            else         PIPE_G3();                                            \
            int t = b0; b0 = b1; b1 = b2; b2 = t;                              \
        }                                                                      \
    }

__global__ __launch_bounds__(512, 2) void qkv_gemm_dma(
    const bf16* __restrict__ xbf, const bf16* __restrict__ wqkv,
    const float* __restrict__ br, const float* __restrict__ bi,
    bf16* __restrict__ qbuf, bf16* __restrict__ kbuf, bf16* __restrict__ vbuf)
{
    const int z = blockIdx.z;
    const bf16* __restrict__ Ap = xbf  + (size_t)z * 4194304;
    const bf16* __restrict__ Bp = wqkv + (size_t)z * 3145728;
    const float* __restrict__ bias = z ? bi : br;

    GEMM_CORE_P(Ap, Bp, 24, 16)

#pragma unroll
    for (int mi = 0; mi < 4; ++mi)
#pragma unroll
        for (int ni = 0; ni < 4; ++ni)
#pragma unroll
            for (int r = 0; r < 4; ++r) {
                int gm = m0 + wm + mi*16 + quad*4 + r;
                int gc = n0 + wn + ni*16 + lc;
                float val = acc[mi][ni][r] + bias[gc];
                int which = gc >> 10, h = (gc >> 6) & 15, hd = gc & 63;
                if (which == 0) val *= QSCALE_;       // pre-scale Q (see header)
                bf16 bv = (bf16)val;
                int b = gm >> 11, n = gm & 2047;
                size_t base = (size_t)((z*BB_ + b)*HEADS_ + h);
                if (which == 0)      qbuf[(base*NN_ + n)*HD_ + hd] = bv;
                else if (which == 1) kbuf[(base*NN_ + n)*HD_ + hd] = bv;
                else                 vbuf[(base*HD_ + hd)*NN_ + n] = bv;   // V transposed
            }
}

__global__ __launch_bounds__(512, 2) void out_gemm_dma(
    const bf16* __restrict__ obuf, const bf16* __restrict__ wout,
    const float* __restrict__ br, const float* __restrict__ bi,
    float* __restrict__ out)
{
    const int z = blockIdx.z;
    const bf16* __restrict__ Ap = obuf + (size_t)z * 4194304;
    const bf16* __restrict__ Bp = wout + (size_t)z * 1048576;
    const float* __restrict__ bias = z ? bi : br;
    float* __restrict__ dst = out + (size_t)z * 4194304;

    GEMM_CORE_P(Ap, Bp, 8, 16)

#pragma unroll
    for (int mi = 0; mi < 4; ++mi)
#pragma unroll
        for (int ni = 0; ni < 4; ++ni)
#pragma unroll
            for (int r = 0; r < 4; ++r) {
                int gm = m0 + wm + mi*16 + quad*4 + r;
                int gc = n0 + wn + ni*16 + lc;
                dst[(size_t)gm*DIM_ + gc] = acc[mi][ni][r] + bias[gc];
            }
}

// ---------------------------------------------------------------------------
// Flash attention v9 (unchanged; at the plain-HIP structural ceiling ~920 TF
// effective): 512 blocks x 8 waves, 16 Q rows/wave; triple-buffered KT=32
// tiles, vmcnt(2) pipe sync, swapped QK^T + K-row perm (P in regs),
// Q pre-scaled (exp2 direct), l via ones-MFMA, merged 16-MFMA S^T cluster.
// ---------------------------------------------------------------------------
#define KT 32
#define NSTEP (NN_/KT)

__global__ __launch_bounds__(512, 4) void attn_fwd(
    const bf16* __restrict__ qbuf, const bf16* __restrict__ kbuf,
    const bf16* __restrict__ vbuf, bf16* __restrict__ obuf)
{
    const int bid = blockIdx.x;          // 0..511
    const int xcd = bid & 7;
    const int loc = bid >> 3;            // 0..63
    const int hb  = xcd*4 + (loc >> 4);  // 0..31  (4 (b,h) streams per XCD)
    const int blk = loc & 15;            // 0..15
    const int b = hb >> 4, h = hb & 15;

    const int tid  = threadIdx.x;
    const int w    = tid >> 6, lane = tid & 63;   // w: 0..7
    const int quad = lane >> 4, lc = lane & 15;
    const int q0   = blk*128 + w*16;     // this wave's 16 Q rows

    __shared__ __align__(16) bf16 KV[3*8192];     // 3 bufs x [Kr|Ki|Vr|Vi] 4KB each

    const size_t hR = (size_t)(b)*HEADS_ + h;
    const size_t hI = (size_t)(BB_ + b)*HEADS_ + h;
    const bf16* qrg = qbuf + hR*NN_*HD_;
    const bf16* qig = qbuf + hI*NN_*HD_;
    const char* krg = (const char*)(kbuf + hR*NN_*HD_);
    const char* kig = (const char*)(kbuf + hI*NN_*HD_);
    const char* vrg = (const char*)(vbuf + hR*HD_*NN_);
    const char* vig = (const char*)(vbuf + hI*HD_*NN_);

    // ---- Q fragments (pre-scaled by QSCALE_ at the GEMM) ----
    const bf16* pr = qrg + (size_t)(q0 + lc)*HD_ + quad*8;
    const bf16* pi = qig + (size_t)(q0 + lc)*HD_ + quad*8;
    bf16x8 qr0 = *(const bf16x8*)(pr);
    bf16x8 qr1 = *(const bf16x8*)(pr + 32);
    bf16x8 qi0 = *(const bf16x8*)(pi);
    bf16x8 qi1 = *(const bf16x8*)(pi + 32);
    bf16x8 nqr0 = neg8(qr0), nqr1 = neg8(qr1);

    // ---- ones B-frag for the l row-sum MFMA ----
    bf16x8 ones;
#pragma unroll
    for (int j = 0; j < 8; ++j) ones[j] = (bf16)1.0f;

    // ---- staging: wave w -> array w>>1 (0=Kr,1=Ki,2=Vr,3=Vi), half w&1 ----
    const int arr = w >> 1, half = w & 1;
    const char* stg_base = (arr == 0) ? krg : (arr == 1) ? kig
                         : (arr == 2) ? vrg : vig;
    size_t lane_off, step_mul, j_mul;
    if (arr < 2) {
        const int rl = lane >> 3;                              // LDS row in DMA grp
        const int p0 = (rl >> 2)*8 + half*4 + (rl & 3);        // perm'd global row
        lane_off = (size_t)p0*128 + (size_t)((lane & 7) ^ rl)*16;
        step_mul = 4096;  j_mul = 2048;                        // DMA B: +16 rows
    } else {
        lane_off = (size_t)half*131072
                 + (size_t)(lane >> 2)*4096 + (size_t)((lane & 3) ^ ((lane >> 3) & 3))*16;
        step_mul = 64;    j_mul = 65536;
    }
    const char* stg0 = stg_base + lane_off;
    const int lds_base = arr*2048 + half*1024;    // elems within buffer

    // ---- hoisted LDS fragment offsets (elems) ----
    int koff[2][2], voff[4];
#pragma unroll
    for (int kb = 0; kb < 2; ++kb)
#pragma unroll
        for (int hf = 0; hf < 2; ++hf) {
            int r = kb*16 + lc;
            koff[kb][hf] = r*64 + (((hf*4 + quad) ^ (r & 7))*8);
        }
#pragma unroll
    for (int vb = 0; vb < 4; ++vb) {
        int r = vb*16 + lc;
        voff[vb] = r*32 + ((quad ^ ((r >> 1) & 3))*8);
    }

    // ---- accumulators / pipeline regs ----
    const fx4 fzero = {0.f, 0.f, 0.f, 0.f};
    fx4 O[2][4];
    fx4 lacc = fzero;                     // l_{quad*4+r} via ones-MFMA
#pragma unroll
    for (int ri = 0; ri < 2; ++ri)
#pragma unroll
        for (int vb = 0; vb < 4; ++vb) O[ri][vb] = fzero;
    bf16x8 pf = {};
    bf16x8 vf[2][4];

    // ---- prologue: stage tiles 0 and 1 ----
    {
        bf16* l = KV + lds_base;
        gl_lds16(stg0,          l);
        gl_lds16(stg0 + j_mul,  l + 512);
        l = KV + 8192 + lds_base;
        gl_lds16(stg0 + step_mul,         l);
        gl_lds16(stg0 + step_mul + j_mul, l + 512);
    }
    PIPE_SYNC();   // drains tile 0 (vmcnt(2) leaves tile 1 in flight)

    int b0 = 0, b1 = 8192, b2 = 16384;
    for (int s = 0; s < NSTEP; ++s) {
        // ---- DMA tile s+2 into buffer b2 (freed at barrier end of s-1) ----
        if (s < NSTEP-2) {
            const char* g = stg0 + (size_t)(s+2)*step_mul;
            bf16* l = KV + b2 + lds_base;
            gl_lds16(g,         l);
            gl_lds16(g + j_mul, l + 512);
        }

        // ---- PV for step s-1 (P + V frags in regs, overlaps everything) ----
        if (s > 0) {
            __builtin_amdgcn_s_setprio(1);
#pragma unroll
            for (int ri = 0; ri < 2; ++ri)
#pragma unroll
                for (int vb = 0; vb < 4; ++vb)
                    O[ri][vb] = __builtin_amdgcn_mfma_f32_16x16x32_bf16(
                        pf, vf[ri][vb], O[ri][vb], 0, 0, 0);
            __builtin_amdgcn_s_setprio(0);
        }

        // ---- K fragments from LDS buffer b0 ----
        bf16x8 kr_[2][2], ki_[2][2];
#pragma unroll
        for (int kb = 0; kb < 2; ++kb)
#pragma unroll
            for (int hf = 0; hf < 2; ++hf) {
                kr_[kb][hf] = *(bf16x8*)&KV[b0 + koff[kb][hf]];
                ki_[kb][hf] = *(bf16x8*)&KV[b0 + 2048 + koff[kb][hf]];
            }

        // ---- S^T(s): ONE 16-MFMA cluster (4 indep 4-chains), no kb fence ----
        fx4 sr[2], si[2];
        __builtin_amdgcn_s_setprio(1);
#pragma unroll
        for (int kb = 0; kb < 2; ++kb) {
            sr[kb] = fzero; si[kb] = fzero;
            sr[kb] = __builtin_amdgcn_mfma_f32_16x16x32_bf16(kr_[kb][0], qr0,  sr[kb], 0,0,0);
            sr[kb] = __builtin_amdgcn_mfma_f32_16x16x32_bf16(kr_[kb][1], qr1,  sr[kb], 0,0,0);
            sr[kb] = __builtin_amdgcn_mfma_f32_16x16x32_bf16(ki_[kb][0], qi0,  sr[kb], 0,0,0);
            sr[kb] = __builtin_amdgcn_mfma_f32_16x16x32_bf16(ki_[kb][1], qi1,  sr[kb], 0,0,0);
            si[kb] = __builtin_amdgcn_mfma_f32_16x16x32_bf16(kr_[kb][0], qi0,  si[kb], 0,0,0);
            si[kb] = __builtin_amdgcn_mfma_f32_16x16x32_bf16(kr_[kb][1], qi1,  si[kb], 0,0,0);
            si[kb] = __builtin_amdgcn_mfma_f32_16x16x32_bf16(ki_[kb][0], nqr0, si[kb], 0,0,0);
            si[kb] = __builtin_amdgcn_mfma_f32_16x16x32_bf16(ki_[kb][1], nqr1, si[kb], 0,0,0);
        }
        __builtin_amdgcn_s_setprio(0);

        // ---- batched softmax (8 elems), then pack (pairable cvt) ----
        float pv8[8];
#pragma unroll
        for (int kb = 0; kb < 2; ++kb)
#pragma unroll
            for (int r4 = 0; r4 < 4; ++r4) {
                float s2 = sr[kb][r4]*sr[kb][r4] + si[kb][r4]*si[kb][r4];
                float mg = __builtin_amdgcn_sqrtf(s2);
                pv8[kb*4 + r4] = __builtin_amdgcn_exp2f(mg);   // Q pre-scaled
            }
#pragma unroll
        for (int j = 0; j < 8; ++j) pf[j] = (bf16)pv8[j];

        // ---- l row-sum via MFMA ----
        lacc = __builtin_amdgcn_mfma_f32_16x16x32_bf16(pf, ones, lacc, 0, 0, 0);

        // ---- pre-read next-iteration V operands (before barrier, from b0) ----
#pragma unroll
        for (int ri = 0; ri < 2; ++ri)
#pragma unroll
            for (int vb = 0; vb < 4; ++vb)
                vf[ri][vb] = *(bf16x8*)&KV[b0 + (2+ri)*2048 + voff[vb]];

        if (s == NSTEP-2) FULL_SYNC();   // last tile: explicit drain
        else              PIPE_SYNC();   // drains tile s+1; tile s+2 in flight
        int t = b0; b0 = b1; b1 = b2; b2 = t;
    }

    // ---- final PV (step NSTEP-1) ----
    __builtin_amdgcn_s_setprio(1);
#pragma unroll
    for (int ri = 0; ri < 2; ++ri)
#pragma unroll
        for (int vb = 0; vb < 4; ++vb)
            O[ri][vb] = __builtin_amdgcn_mfma_f32_16x16x32_bf16(
                pf, vf[ri][vb], O[ri][vb], 0, 0, 0);
    __builtin_amdgcn_s_setprio(0);

    // ---- normalize + store: lacc[r] is already l for q-row quad*4+r ----
    float inv[4];
#pragma unroll
    for (int r = 0; r < 4; ++r) inv[r] = 1.f / lacc[r];

    bf16* obr = obuf + ((size_t)(b)*NN_)*DIM_;
    bf16* obi = obuf + ((size_t)(BB_ + b)*NN_)*DIM_;
#pragma unroll
    for (int vb = 0; vb < 4; ++vb)
#pragma unroll
        for (int r = 0; r < 4; ++r) {
            int gn = q0 + quad*4 + r;
            int gc = h*HD_ + vb*16 + lc;
            obr[(size_t)gn*DIM_ + gc] = (bf16)(O[0][vb][r] * inv[r]);
            obi[(size_t)gn*DIM_ + gc] = (bf16)(O[1][vb][r] * inv[r]);
        }
}

// ---------------------------------------------------------------------------
// Legacy (round-3) GEMMs — fallback when ws_size < 84 MB.
// ---------------------------------------------------------------------------
__global__ __launch_bounds__(256) void qkv_gemm_legacy(
    const float* __restrict__ xr, const float* __restrict__ xi,
    const float* __restrict__ Wr, const float* __restrict__ Wi,
    const float* __restrict__ br, const float* __restrict__ bi,
    bf16* __restrict__ qbuf, bf16* __restrict__ kbuf, bf16* __restrict__ vbuf)
{
    const int z = blockIdx.z;
    const float* __restrict__ A    = z ? xi : xr;
    const float* __restrict__ W    = z ? Wi : Wr;
    const float* __restrict__ bias = z ? bi : br;
    const int n0 = blockIdx.x * 128;
    const int m0 = blockIdx.y * 128;

    __shared__ bf16 As[128*40];
    __shared__ bf16 Bs[128*40];

    const int tid  = threadIdx.x;
    const int w    = tid >> 6, lane = tid & 63;
    const int quad = lane >> 4, lc = lane & 15;
    const int wm   = (w >> 1) * 64, wn = (w & 1) * 64;

    const fx4 fzero = {0.f, 0.f, 0.f, 0.f};
    fx4 acc[4][4];
#pragma unroll
    for (int mi = 0; mi < 4; ++mi)
#pragma unroll
        for (int ni = 0; ni < 4; ++ni) acc[mi][ni] = fzero;

    for (int k0 = 0; k0 < DIM_; k0 += 32) {
#pragma unroll
        for (int it = 0; it < 2; ++it) {
            int flat = it*2048 + tid*8;
            int row = flat >> 5, col = flat & 31;
            const float* pa = A + (size_t)(m0+row)*DIM_ + k0 + col;
            const float* pb = W + (size_t)(n0+row)*DIM_ + k0 + col;
            fx4 a0 = *(const fx4*)pa, a1 = *(const fx4*)(pa+4);
            fx4 b0 = *(const fx4*)pb, b1 = *(const fx4*)(pb+4);
            bf16x8 av, bv;
#pragma unroll
            for (int j = 0; j < 4; ++j) {
                av[j] = (bf16)a0[j]; av[j+4] = (bf16)a1[j];
                bv[j] = (bf16)b0[j]; bv[j+4] = (bf16)b1[j];
            }
            *(bf16x8*)&As[row*40 + col] = av;
            *(bf16x8*)&Bs[row*40 + col] = bv;
        }
        __syncthreads();

        bf16x8 af[4], bfr[4];
#pragma unroll
        for (int mi = 0; mi < 4; ++mi) af[mi]  = *(bf16x8*)&As[(wm + mi*16 + lc)*40 + quad*8];
#pragma unroll
        for (int ni = 0; ni < 4; ++ni) bfr[ni] = *(bf16x8*)&Bs[(wn + ni*16 + lc)*40 + quad*8];
#pragma unroll
        for (int mi = 0; mi < 4; ++mi)
#pragma unroll
            for (int ni = 0; ni < 4; ++ni)
                acc[mi][ni] = __builtin_amdgcn_mfma_f32_16x16x32_bf16(af[mi], bfr[ni], acc[mi][ni], 0, 0, 0);
        __syncthreads();
    }

#pragma unroll
    for (int mi = 0; mi < 4; ++mi)
#pragma unroll
        for (int ni = 0; ni < 4; ++ni)
#pragma unroll
            for (int r = 0; r < 4; ++r) {
                int gm = m0 + wm + mi*16 + quad*4 + r;
                int gc = n0 + wn + ni*16 + lc;
                float val = acc[mi][ni][r] + bias[gc];
                int which = gc >> 10, h = (gc >> 6) & 15, hd = gc & 63;
                if (which == 0) val *= QSCALE_;       // pre-scale Q
                bf16 bv = (bf16)val;
                int b = gm >> 11, n = gm & 2047;
                size_t base = (size_t)((z*BB_ + b)*HEADS_ + h);
                if (which == 0)      qbuf[(base*NN_ + n)*HD_ + hd] = bv;
                else if (which == 1) kbuf[(base*NN_ + n)*HD_ + hd] = bv;
                else                 vbuf[(base*HD_ + hd)*NN_ + n] = bv;
            }
}

__global__ __launch_bounds__(256) void out_gemm_legacy(
    const bf16* __restrict__ obuf,
    const float* __restrict__ Wr, const float* __restrict__ Wi,
    const float* __restrict__ br, const float* __restrict__ bi,
    float* __restrict__ out)
{
    const int z = blockIdx.z;
    const bf16*  __restrict__ A    = obuf + (size_t)z * MTOT_ * DIM_;
    const float* __restrict__ W    = z ? Wi : Wr;
    const float* __restrict__ bias = z ? bi : br;
    float* __restrict__ dst        = out + (size_t)z * MTOT_ * DIM_;
    const int n0 = blockIdx.x * 128;
    const int m0 = blockIdx.y * 128;

    __shared__ bf16 As[128*40];
    __shared__ bf16 Bs[128*40];

    const int tid  = threadIdx.x;
    const int w    = tid >> 6, lane = tid & 63;
    const int quad = lane >> 4, lc = lane & 15;
    const int wm   = (w >> 1) * 64, wn = (w & 1) * 64;

    const fx4 fzero = {0.f, 0.f, 0.f, 0.f};
    fx4 acc[4][4];
#pragma unroll
    for (int mi = 0; mi < 4; ++mi)
#pragma unroll
        for (int ni = 0; ni < 4; ++ni) acc[mi][ni] = fzero;

    for (int k0 = 0; k0 < DIM_; k0 += 32) {
#pragma unroll
        for (int it = 0; it < 2; ++it) {
            int flat = it*2048 + tid*8;
            int row = flat >> 5, col = flat & 31;
            *(bf16x8*)&As[row*40 + col] = *(const bf16x8*)(A + (size_t)(m0+row)*DIM_ + k0 + col);
            const float* pb = W + (size_t)(n0+row)*DIM_ + k0 + col;
            fx4 b0 = *(const fx4*)pb, b1 = *(const fx4*)(pb+4);
            bf16x8 bv;
#pragma unroll
            for (int j = 0; j < 4; ++j) { bv[j] = (bf16)b0[j]; bv[j+4] = (bf16)b1[j]; }
            *(bf16x8*)&Bs[row*40 + col] = bv;
        }
        __syncthreads();

        bf16x8 af[4], bfr[4];
#pragma unroll
        for (int mi = 0; mi < 4; ++mi) af[mi]  = *(bf16x8*)&As[(wm + mi*16 + lc)*40 + quad*8];
#pragma unroll
        for (int ni = 0; ni < 4; ++ni) bfr[ni] = *(bf16x8*)&Bs[(wn + ni*16 + lc)*40 + quad*8];
#pragma unroll
        for (int mi = 0; mi < 4; ++mi)
#pragma unroll
            for (int ni = 0; ni < 4; ++ni)
                acc[mi][ni] = __builtin_amdgcn_mfma_f32_16x16x32_bf16(af[mi], bfr[ni], acc[mi][ni], 0, 0, 0);
        __syncthreads();
    }

#pragma unroll
    for (int mi = 0; mi < 4; ++mi)
#pragma unroll
        for (int ni = 0; ni < 4; ++ni)
#pragma unroll
            for (int r = 0; r < 4; ++r) {
                int gm = m0 + wm + mi*16 + quad*4 + r;
                int gc = n0 + wn + ni*16 + lc;
                dst[(size_t)gm*DIM_ + gc] = acc[mi][ni][r] + bias[gc];
            }
}

// ---------------------------------------------------------------------------
extern "C" void kernel_launch(void* const* d_in, const int* in_sizes, int n_in,
                              void* d_out, int out_size, void* d_ws, size_t ws_size,
                              hipStream_t stream) {
    const float* xr  = (const float*)d_in[0];
    const float* xi  = (const float*)d_in[1];
    const float* Wqr = (const float*)d_in[2];
    const float* bqr = (const float*)d_in[3];
    const float* Wqi = (const float*)d_in[4];
    const float* bqi = (const float*)d_in[5];
    const float* Wor = (const float*)d_in[6];
    const float* bor = (const float*)d_in[7];
    const float* Woi = (const float*)d_in[8];
    const float* boi = (const float*)d_in[9];
    float* out = (float*)d_out;

    bf16* ws = (bf16*)d_ws;
    const size_t NEED = 83886080ull;

    if (ws_size >= NEED) {
        bf16* xbf  = ws;               // reused as obuf after qkv
        bf16* wqkv = ws + 8388608;
        bf16* wout = ws + 14680064;
        bf16* qb   = ws + 16777216;
        bf16* kb   = ws + 25165824;
        bf16* vb   = ws + 33554432;
        bf16* obuf = xbf;

        cvt_prepass<<<dim3(8192), 256, 0, stream>>>(xr, xi, Wqr, Wqi, Wor, Woi,
                                                    xbf, wqkv, wout);
        qkv_gemm_dma<<<dim3(24, 16, 2), 512, 0, stream>>>(xbf, wqkv, bqr, bqi,
                                                          qb, kb, vb);
        attn_fwd<<<dim3(512), 512, 0, stream>>>(qb, kb, vb, obuf);
        out_gemm_dma<<<dim3(8, 16, 2), 512, 0, stream>>>(obuf, wout, bor, boi, out);
    } else {
        const size_t per = (size_t)2 * BB_ * HEADS_ * NN_ * HD_;
        bf16* qb   = ws;
        bf16* kb   = ws + per;
        bf16* vb   = ws + 2*per;
        bf16* obuf = ws + 3*per;
        qkv_gemm_legacy<<<dim3(24, 32, 2), 256, 0, stream>>>(xr, xi, Wqr, Wqi,
                                                             bqr, bqi, qb, kb, vb);
        attn_fwd<<<dim3(512), 512, 0, stream>>>(qb, kb, vb, obuf);
        out_gemm_legacy<<<dim3(8, 32, 2), 256, 0, stream>>>(obuf, Wor, Woi,
                                                            bor, boi, out);
    }
}

// Round 8
// 321.904 us; speedup vs baseline: 1.0213x; 1.0213x over previous
//
#include <hip/hip_runtime.h>

// ComplexMultiHeadAttention: B=2, N=2048, D=1024, H=16, hd=64
// Fast path (ws >= 84MB): [cvt_prepass f32->bf16] -> [qkv_gemm_dma] -> [attn_fwd]
//                         -> [out_gemm_dma] ; obuf aliases xbf (dead after qkv).
// Fallback (small ws): legacy GEMMs + same attn.
//
// Session ledger (R0..R8):
//  R1  attn: swapped QK^T + K-row perm, P in regs       356.3 -> 337.5
//  R2  attn 32-row waves: REGRESSED (occupancy)          (350.3, reverted)
//  R3  attn: Q pre-scale + ones-MFMA l + setprio         340.5 (counters hit,
//      wall ~flat -> intra-wave serialization diagnosed)
//  R4  attn superstep/4-buf: REGRESSED (serializer is intra-wave)
//  R5  attn merged 16-MFMA cluster: neutral -> attn at ~920 TF ceiling
//  R6  GEMMs: counted-vmcnt distance-2 triple-buffer     324.1  <-- BEST
//  R7  GEMMs 256x128: REGRESSED (+4.7; 1.5-round dispatch tail)
//  R8  revert to R6 config (2.0-round quantization at every kernel)

#define DIM_   1024
#define HEADS_ 16
#define HD_    64
#define BB_    2
#define NN_    2048
#define MTOT_  (BB_*NN_)      // 4096
#define SCALE_ 0.125f
// Q is pre-scaled by SCALE_*log2(e) in the qkv GEMM epilogue, so attn's
// softmax is pv = exp2(|S|) directly.
#define QSCALE_ 0.1803368801111243f   // 0.125 * 1.44269504

typedef __bf16 bf16;
typedef __bf16 bf16x8 __attribute__((ext_vector_type(8)));
typedef short  s16x8  __attribute__((ext_vector_type(8)));
typedef float  fx4    __attribute__((ext_vector_type(4)));

__device__ __forceinline__ bf16x8 neg8(bf16x8 v) {
    s16x8 s;
    __builtin_memcpy(&s, &v, sizeof(s));
    s ^= (short)0x8000;
    bf16x8 r;
    __builtin_memcpy(&r, &s, sizeof(r));
    return r;
}

__device__ __forceinline__ void gl_lds16(const void* g, void* l) {
    __builtin_amdgcn_global_load_lds(
        (const __attribute__((address_space(1))) unsigned int*)g,
        (__attribute__((address_space(3))) unsigned int*)l, 16, 0, 0);
}

// Counted-vmcnt pipeline barriers (attn: 2 DMAs/wave/tile; GEMM: 4).
#define PIPE_SYNC() asm volatile("s_waitcnt vmcnt(2)\n\ts_barrier" ::: "memory")
#define PIPE_G()    asm volatile("s_waitcnt vmcnt(4)\n\ts_barrier" ::: "memory")
#define FULL_SYNC() asm volatile("s_waitcnt vmcnt(0)\n\ts_barrier" ::: "memory")

// ---------------------------------------------------------------------------
// Prepass: f32 -> bf16 for x (8.39M), Wqkv (6.29M), Wout (2.1M). 8192 blocks.
// BW-floor (~100MB moved ~= 16us at 6.3 TB/s).
// ---------------------------------------------------------------------------
__global__ __launch_bounds__(256) void cvt_prepass(
    const float* __restrict__ xr, const float* __restrict__ xi,
    const float* __restrict__ wqr, const float* __restrict__ wqi,
    const float* __restrict__ wor, const float* __restrict__ woi,
    bf16* __restrict__ xbf, bf16* __restrict__ wqkv, bf16* __restrict__ wout)
{
    const int bid = blockIdx.x;
    const float* src; bf16* dst; int rel;
    if      (bid < 2048) { src = xr;  dst = xbf;           rel = bid; }
    else if (bid < 4096) { src = xi;  dst = xbf + 4194304; rel = bid - 2048; }
    else if (bid < 5632) { src = wqr; dst = wqkv;          rel = bid - 4096; }
    else if (bid < 7168) { src = wqi; dst = wqkv + 3145728; rel = bid - 5632; }
    else if (bid < 7680) { src = wor; dst = wout;          rel = bid - 7168; }
    else                 { src = woi; dst = wout + 1048576; rel = bid - 7680; }
    size_t base = (size_t)rel * 2048 + (size_t)threadIdx.x * 8;
    fx4 a = *(const fx4*)(src + base);
    fx4 b = *(const fx4*)(src + base + 4);
    bf16x8 o;
#pragma unroll
    for (int j = 0; j < 4; ++j) { o[j] = (bf16)a[j]; o[j+4] = (bf16)b[j]; }
    *(bf16x8*)(dst + base) = o;
}

// ---------------------------------------------------------------------------
// Pipelined GEMM core v2 (R6, best measured): C[m,c] = A[m,:].B[c,:],
// A/B bf16 row-major [..][1024]. 128x128 tile, BK=32, TRIPLE-buffered
// distance-2 prefetch via global_load_lds with counted vmcnt(4) -- tile s+2's
// 4 DMAs stay in flight across the barrier; the barrier drains only s+1
// (removes the m97 vmcnt(0) drain stall). 48KB LDS -> 3 blocks/CU ->
// 12 waves/CU AND perfect dispatch quantization: qkv 1536 blocks / 768
// resident = 2.0 rounds (R7's 256x128 at 2/CU gave 1.5 rounds -> tail loss).
// LDS chunk swizzle: chunk ^ (r&3) ^ ((r>>2)&3) on BOTH stage and read sides
// => frag reads only 2-way bank-aliased (free, m136). XCD-aware bijective
// block swizzle (total blocks % 8 == 0).
// ---------------------------------------------------------------------------
#define GEMM_CORE_P(Aptr, Bptr, NWGX)                                          \
    __shared__ __align__(16) bf16 LS[3*8192];                                  \
    const int tid  = threadIdx.x;                                              \
    const int w    = tid >> 6, lane = tid & 63;                                \
    const int quad = lane >> 4, lc = lane & 15;                                \
    const int wm   = (w >> 1) * 64, wn = (w & 1) * 64;                         \
    const int rl   = lane >> 2, cl = lane & 3;                                 \
    const int swc  = cl ^ ((rl & 3) ^ ((rl >> 2) & 3));                        \
    const int rsw  = (quad ^ ((lc & 3) ^ ((lc >> 2) & 3))) * 8;                \
    int flat = blockIdx.y * (NWGX) + blockIdx.x;                               \
    flat = (flat & 7) * (((NWGX) * 32) / 8) + (flat >> 3);                     \
    const int m0 = (flat / (NWGX)) * 128;                                      \
    const int n0 = (flat % (NWGX)) * 128;                                      \
    const fx4 fzero = {0.f, 0.f, 0.f, 0.f};                                    \
    fx4 acc[4][4];                                                             \
    _Pragma("unroll")                                                          \
    for (int mi = 0; mi < 4; ++mi)                                             \
        _Pragma("unroll")                                                      \
        for (int ni = 0; ni < 4; ++ni) acc[mi][ni] = fzero;                    \
    const bf16* aSrc = Aptr + (size_t)(m0 + w*32 + rl)*DIM_ + swc*8;           \
    const bf16* bSrc = Bptr + (size_t)(n0 + w*32 + rl)*DIM_ + swc*8;           \
    auto STG = [&](int kk, int bb) {                                           \
        gl_lds16(aSrc + kk,                  LS + bb + w*1024);                \
        gl_lds16(aSrc + kk + 16*DIM_,        LS + bb + w*1024 + 512);          \
        gl_lds16(bSrc + kk,                  LS + bb + 4096 + w*1024);         \
        gl_lds16(bSrc + kk + 16*DIM_,        LS + bb + 4096 + w*1024 + 512);   \
    };                                                                         \
    STG(0, 0);                                                                 \
    STG(32, 8192);                                                             \
    PIPE_G();                                                                  \
    {                                                                          \
        int b0 = 0, b1 = 8192, b2 = 16384;                                     \
        for (int s = 0; s < 32; ++s) {                                         \
            if (s < 30) STG((s + 2) * 32, b2);                                 \
            bf16x8 af[4], bfr[4];                                              \
            _Pragma("unroll")                                                  \
            for (int mi = 0; mi < 4; ++mi)                                     \
                af[mi] = *(bf16x8*)&LS[b0 + (wm + mi*16 + lc)*32 + rsw];       \
            _Pragma("unroll")                                                  \
            for (int ni = 0; ni < 4; ++ni)                                     \
                bfr[ni] = *(bf16x8*)&LS[b0 + 4096 + (wn + ni*16 + lc)*32 + rsw]; \
            _Pragma("unroll")                                                  \
            for (int mi = 0; mi < 4; ++mi)                                     \
                _Pragma("unroll")                                              \
                for (int ni = 0; ni < 4; ++ni)                                 \
                    acc[mi][ni] = __builtin_amdgcn_mfma_f32_16x16x32_bf16(     \
                        af[mi], bfr[ni], acc[mi][ni], 0, 0, 0);                \
            if (s == 30) FULL_SYNC();                                          \
            else         PIPE_G();                                             \
            int t = b0; b0 = b1; b1 = b2; b2 = t;                              \
        }                                                                      \
    }

__global__ __launch_bounds__(256, 3) void qkv_gemm_dma(
    const bf16* __restrict__ xbf, const bf16* __restrict__ wqkv,
    const float* __restrict__ br, const float* __restrict__ bi,
    bf16* __restrict__ qbuf, bf16* __restrict__ kbuf, bf16* __restrict__ vbuf)
{
    const int z = blockIdx.z;
    const bf16* __restrict__ Ap = xbf  + (size_t)z * 4194304;
    const bf16* __restrict__ Bp = wqkv + (size_t)z * 3145728;
    const float* __restrict__ bias = z ? bi : br;

    GEMM_CORE_P(Ap, Bp, 24)

#pragma unroll
    for (int mi = 0; mi < 4; ++mi)
#pragma unroll
        for (int ni = 0; ni < 4; ++ni)
#pragma unroll
            for (int r = 0; r < 4; ++r) {
                int gm = m0 + wm + mi*16 + quad*4 + r;
                int gc = n0 + wn + ni*16 + lc;
                float val = acc[mi][ni][r] + bias[gc];
                int which = gc >> 10, h = (gc >> 6) & 15, hd = gc & 63;
                if (which == 0) val *= QSCALE_;       // pre-scale Q (see header)
                bf16 bv = (bf16)val;
                int b = gm >> 11, n = gm & 2047;
                size_t base = (size_t)((z*BB_ + b)*HEADS_ + h);
                if (which == 0)      qbuf[(base*NN_ + n)*HD_ + hd] = bv;
                else if (which == 1) kbuf[(base*NN_ + n)*HD_ + hd] = bv;
                else                 vbuf[(base*HD_ + hd)*NN_ + n] = bv;   // V transposed
            }
}

__global__ __launch_bounds__(256, 3) void out_gemm_dma(
    const bf16* __restrict__ obuf, const bf16* __restrict__ wout,
    const float* __restrict__ br, const float* __restrict__ bi,
    float* __restrict__ out)
{
    const int z = blockIdx.z;
    const bf16* __restrict__ Ap = obuf + (size_t)z * 4194304;
    const bf16* __restrict__ Bp = wout + (size_t)z * 1048576;
    const float* __restrict__ bias = z ? bi : br;
    float* __restrict__ dst = out + (size_t)z * 4194304;

    GEMM_CORE_P(Ap, Bp, 8)

#pragma unroll
    for (int mi = 0; mi < 4; ++mi)
#pragma unroll
        for (int ni = 0; ni < 4; ++ni)
#pragma unroll
            for (int r = 0; r < 4; ++r) {
                int gm = m0 + wm + mi*16 + quad*4 + r;
                int gc = n0 + wn + ni*16 + lc;
                dst[(size_t)gm*DIM_ + gc] = acc[mi][ni][r] + bias[gc];
            }
}

// ---------------------------------------------------------------------------
// Flash attention v9 (at the plain-HIP 2-barrier structural ceiling, ~920 TF
// effective; 3 alternative schedules all landed 112-114us): 512 blocks x
// 8 waves, 16 Q rows/wave; triple-buffered KT=32 tiles, vmcnt(2) pipe sync,
// swapped QK^T + K-row perm (P in regs), Q pre-scaled (exp2 direct), l via
// ones-MFMA, merged 16-MFMA S^T cluster. 2 blocks/CU x 256 CUs = 512 = grid
// -> 1.0 dispatch rounds.
// ---------------------------------------------------------------------------
#define KT 32
#define NSTEP (NN_/KT)

__global__ __launch_bounds__(512, 4) void attn_fwd(
    const bf16* __restrict__ qbuf, const bf16* __restrict__ kbuf,
    const bf16* __restrict__ vbuf, bf16* __restrict__ obuf)
{
    const int bid = blockIdx.x;          // 0..511
    const int xcd = bid & 7;
    const int loc = bid >> 3;            // 0..63
    const int hb  = xcd*4 + (loc >> 4);  // 0..31  (4 (b,h) streams per XCD)
    const int blk = loc & 15;            // 0..15
    const int b = hb >> 4, h = hb & 15;

    const int tid  = threadIdx.x;
    const int w    = tid >> 6, lane = tid & 63;   // w: 0..7
    const int quad = lane >> 4, lc = lane & 15;
    const int q0   = blk*128 + w*16;     // this wave's 16 Q rows

    __shared__ __align__(16) bf16 KV[3*8192];     // 3 bufs x [Kr|Ki|Vr|Vi] 4KB each

    const size_t hR = (size_t)(b)*HEADS_ + h;
    const size_t hI = (size_t)(BB_ + b)*HEADS_ + h;
    const bf16* qrg = qbuf + hR*NN_*HD_;
    const bf16* qig = qbuf + hI*NN_*HD_;
    const char* krg = (const char*)(kbuf + hR*NN_*HD_);
    const char* kig = (const char*)(kbuf + hI*NN_*HD_);
    const char* vrg = (const char*)(vbuf + hR*HD_*NN_);
    const char* vig = (const char*)(vbuf + hI*HD_*NN_);

    // ---- Q fragments (pre-scaled by QSCALE_ at the GEMM) ----
    const bf16* pr = qrg + (size_t)(q0 + lc)*HD_ + quad*8;
    const bf16* pi = qig + (size_t)(q0 + lc)*HD_ + quad*8;
    bf16x8 qr0 = *(const bf16x8*)(pr);
    bf16x8 qr1 = *(const bf16x8*)(pr + 32);
    bf16x8 qi0 = *(const bf16x8*)(pi);
    bf16x8 qi1 = *(const bf16x8*)(pi + 32);
    bf16x8 nqr0 = neg8(qr0), nqr1 = neg8(qr1);

    // ---- ones B-frag for the l row-sum MFMA ----
    bf16x8 ones;
#pragma unroll
    for (int j = 0; j < 8; ++j) ones[j] = (bf16)1.0f;

    // ---- staging: wave w -> array w>>1 (0=Kr,1=Ki,2=Vr,3=Vi), half w&1 ----
    const int arr = w >> 1, half = w & 1;
    const char* stg_base = (arr == 0) ? krg : (arr == 1) ? kig
                         : (arr == 2) ? vrg : vig;
    size_t lane_off, step_mul, j_mul;
    if (arr < 2) {
        const int rl = lane >> 3;                              // LDS row in DMA grp
        const int p0 = (rl >> 2)*8 + half*4 + (rl & 3);        // perm'd global row
        lane_off = (size_t)p0*128 + (size_t)((lane & 7) ^ rl)*16;
        step_mul = 4096;  j_mul = 2048;                        // DMA B: +16 rows
    } else {
        lane_off = (size_t)half*131072
                 + (size_t)(lane >> 2)*4096 + (size_t)((lane & 3) ^ ((lane >> 3) & 3))*16;
        step_mul = 64;    j_mul = 65536;
    }
    const char* stg0 = stg_base + lane_off;
    const int lds_base = arr*2048 + half*1024;    // elems within buffer

    // ---- hoisted LDS fragment offsets (elems) ----
    int koff[2][2], voff[4];
#pragma unroll
    for (int kb = 0; kb < 2; ++kb)
#pragma unroll
        for (int hf = 0; hf < 2; ++hf) {
            int r = kb*16 + lc;
            koff[kb][hf] = r*64 + (((hf*4 + quad) ^ (r & 7))*8);
        }
#pragma unroll
    for (int vb = 0; vb < 4; ++vb) {
        int r = vb*16 + lc;
        voff[vb] = r*32 + ((quad ^ ((r >> 1) & 3))*8);
    }

    // ---- accumulators / pipeline regs ----
    const fx4 fzero = {0.f, 0.f, 0.f, 0.f};
    fx4 O[2][4];
    fx4 lacc = fzero;                     // l_{quad*4+r} via ones-MFMA
#pragma unroll
    for (int ri = 0; ri < 2; ++ri)
#pragma unroll
        for (int vb = 0; vb < 4; ++vb) O[ri][vb] = fzero;
    bf16x8 pf = {};
    bf16x8 vf[2][4];

    // ---- prologue: stage tiles 0 and 1 ----
    {
        bf16* l = KV + lds_base;
        gl_lds16(stg0,          l);
        gl_lds16(stg0 + j_mul,  l + 512);
        l = KV + 8192 + lds_base;
        gl_lds16(stg0 + step_mul,         l);
        gl_lds16(stg0 + step_mul + j_mul, l + 512);
    }
    PIPE_SYNC();   // drains tile 0 (vmcnt(2) leaves tile 1 in flight)

    int b0 = 0, b1 = 8192, b2 = 16384;
    for (int s = 0; s < NSTEP; ++s) {
        // ---- DMA tile s+2 into buffer b2 (freed at barrier end of s-1) ----
        if (s < NSTEP-2) {
            const char* g = stg0 + (size_t)(s+2)*step_mul;
            bf16* l = KV + b2 + lds_base;
            gl_lds16(g,         l);
            gl_lds16(g + j_mul, l + 512);
        }

        // ---- PV for step s-1 (P + V frags in regs, overlaps everything) ----
        if (s > 0) {
            __builtin_amdgcn_s_setprio(1);
#pragma unroll
            for (int ri = 0; ri < 2; ++ri)
#pragma unroll
                for (int vb = 0; vb < 4; ++vb)
                    O[ri][vb] = __builtin_amdgcn_mfma_f32_16x16x32_bf16(
                        pf, vf[ri][vb], O[ri][vb], 0, 0, 0);
            __builtin_amdgcn_s_setprio(0);
        }

        // ---- K fragments from LDS buffer b0 ----
        bf16x8 kr_[2][2], ki_[2][2];
#pragma unroll
        for (int kb = 0; kb < 2; ++kb)
#pragma unroll
            for (int hf = 0; hf < 2; ++hf) {
                kr_[kb][hf] = *(bf16x8*)&KV[b0 + koff[kb][hf]];
                ki_[kb][hf] = *(bf16x8*)&KV[b0 + 2048 + koff[kb][hf]];
            }

        // ---- S^T(s): ONE 16-MFMA cluster (4 indep 4-chains), no kb fence ----
        fx4 sr[2], si[2];
        __builtin_amdgcn_s_setprio(1);
#pragma unroll
        for (int kb = 0; kb < 2; ++kb) {
            sr[kb] = fzero; si[kb] = fzero;
            sr[kb] = __builtin_amdgcn_mfma_f32_16x16x32_bf16(kr_[kb][0], qr0,  sr[kb], 0,0,0);
            sr[kb] = __builtin_amdgcn_mfma_f32_16x16x32_bf16(kr_[kb][1], qr1,  sr[kb], 0,0,0);
            sr[kb] = __builtin_amdgcn_mfma_f32_16x16x32_bf16(ki_[kb][0], qi0,  sr[kb], 0,0,0);
            sr[kb] = __builtin_amdgcn_mfma_f32_16x16x32_bf16(ki_[kb][1], qi1,  sr[kb], 0,0,0);
            si[kb] = __builtin_amdgcn_mfma_f32_16x16x32_bf16(kr_[kb][0], qi0,  si[kb], 0,0,0);
            si[kb] = __builtin_amdgcn_mfma_f32_16x16x32_bf16(kr_[kb][1], qi1,  si[kb], 0,0,0);
            si[kb] = __builtin_amdgcn_mfma_f32_16x16x32_bf16(ki_[kb][0], nqr0, si[kb], 0,0,0);
            si[kb] = __builtin_amdgcn_mfma_f32_16x16x32_bf16(ki_[kb][1], nqr1, si[kb], 0,0,0);
        }
        __builtin_amdgcn_s_setprio(0);

        // ---- batched softmax (8 elems), then pack (pairable cvt) ----
        float pv8[8];
#pragma unroll
        for (int kb = 0; kb < 2; ++kb)
#pragma unroll
            for (int r4 = 0; r4 < 4; ++r4) {
                float s2 = sr[kb][r4]*sr[kb][r4] + si[kb][r4]*si[kb][r4];
                float mg = __builtin_amdgcn_sqrtf(s2);
                pv8[kb*4 + r4] = __builtin_amdgcn_exp2f(mg);   // Q pre-scaled
            }
#pragma unroll
        for (int j = 0; j < 8; ++j) pf[j] = (bf16)pv8[j];

        // ---- l row-sum via MFMA ----
        lacc = __builtin_amdgcn_mfma_f32_16x16x32_bf16(pf, ones, lacc, 0, 0, 0);

        // ---- pre-read next-iteration V operands (before barrier, from b0) ----
#pragma unroll
        for (int ri = 0; ri < 2; ++ri)
#pragma unroll
            for (int vb = 0; vb < 4; ++vb)
                vf[ri][vb] = *(bf16x8*)&KV[b0 + (2+ri)*2048 + voff[vb]];

        if (s == NSTEP-2) FULL_SYNC();   // last tile: explicit drain
        else              PIPE_SYNC();   // drains tile s+1; tile s+2 in flight
        int t = b0; b0 = b1; b1 = b2; b2 = t;
    }

    // ---- final PV (step NSTEP-1) ----
    __builtin_amdgcn_s_setprio(1);
#pragma unroll
    for (int ri = 0; ri < 2; ++ri)
#pragma unroll
        for (int vb = 0; vb < 4; ++vb)
            O[ri][vb] = __builtin_amdgcn_mfma_f32_16x16x32_bf16(
                pf, vf[ri][vb], O[ri][vb], 0, 0, 0);
    __builtin_amdgcn_s_setprio(0);

    // ---- normalize + store: lacc[r] is already l for q-row quad*4+r ----
    float inv[4];
#pragma unroll
    for (int r = 0; r < 4; ++r) inv[r] = 1.f / lacc[r];

    bf16* obr = obuf + ((size_t)(b)*NN_)*DIM_;
    bf16* obi = obuf + ((size_t)(BB_ + b)*NN_)*DIM_;
#pragma unroll
    for (int vb = 0; vb < 4; ++vb)
#pragma unroll
        for (int r = 0; r < 4; ++r) {
            int gn = q0 + quad*4 + r;
            int gc = h*HD_ + vb*16 + lc;
            obr[(size_t)gn*DIM_ + gc] = (bf16)(O[0][vb][r] * inv[r]);
            obi[(size_t)gn*DIM_ + gc] = (bf16)(O[1][vb][r] * inv[r]);
        }
}

// ---------------------------------------------------------------------------
// Legacy (round-3) GEMMs — fallback when ws_size < 84 MB.
// ---------------------------------------------------------------------------
__global__ __launch_bounds__(256) void qkv_gemm_legacy(
    const float* __restrict__ xr, const float* __restrict__ xi,
    const float* __restrict__ Wr, const float* __restrict__ Wi,
    const float* __restrict__ br, const float* __restrict__ bi,
    bf16* __restrict__ qbuf, bf16* __restrict__ kbuf, bf16* __restrict__ vbuf)
{
    const int z = blockIdx.z;
    const float* __restrict__ A    = z ? xi : xr;
    const float* __restrict__ W    = z ? Wi : Wr;
    const float* __restrict__ bias = z ? bi : br;
    const int n0 = blockIdx.x * 128;
    const int m0 = blockIdx.y * 128;

    __shared__ bf16 As[128*40];
    __shared__ bf16 Bs[128*40];

    const int tid  = threadIdx.x;
    const int w    = tid >> 6, lane = tid & 63;
    const int quad = lane >> 4, lc = lane & 15;
    const int wm   = (w >> 1) * 64, wn = (w & 1) * 64;

    const fx4 fzero = {0.f, 0.f, 0.f, 0.f};
    fx4 acc[4][4];
#pragma unroll
    for (int mi = 0; mi < 4; ++mi)
#pragma unroll
        for (int ni = 0; ni < 4; ++ni) acc[mi][ni] = fzero;

    for (int k0 = 0; k0 < DIM_; k0 += 32) {
#pragma unroll
        for (int it = 0; it < 2; ++it) {
            int flat = it*2048 + tid*8;
            int row = flat >> 5, col = flat & 31;
            const float* pa = A + (size_t)(m0+row)*DIM_ + k0 + col;
            const float* pb = W + (size_t)(n0+row)*DIM_ + k0 + col;
            fx4 a0 = *(const fx4*)pa, a1 = *(const fx4*)(pa+4);
            fx4 b0 = *(const fx4*)pb, b1 = *(const fx4*)(pb+4);
            bf16x8 av, bv;
#pragma unroll
            for (int j = 0; j < 4; ++j) {
                av[j] = (bf16)a0[j]; av[j+4] = (bf16)a1[j];
                bv[j] = (bf16)b0[j]; bv[j+4] = (bf16)b1[j];
            }
            *(bf16x8*)&As[row*40 + col] = av;
            *(bf16x8*)&Bs[row*40 + col] = bv;
        }
        __syncthreads();

        bf16x8 af[4], bfr[4];
#pragma unroll
        for (int mi = 0; mi < 4; ++mi) af[mi]  = *(bf16x8*)&As[(wm + mi*16 + lc)*40 + quad*8];
#pragma unroll
        for (int ni = 0; ni < 4; ++ni) bfr[ni] = *(bf16x8*)&Bs[(wn + ni*16 + lc)*40 + quad*8];
#pragma unroll
        for (int mi = 0; mi < 4; ++mi)
#pragma unroll
            for (int ni = 0; ni < 4; ++ni)
                acc[mi][ni] = __builtin_amdgcn_mfma_f32_16x16x32_bf16(af[mi], bfr[ni], acc[mi][ni], 0, 0, 0);
        __syncthreads();
    }

#pragma unroll
    for (int mi = 0; mi < 4; ++mi)
#pragma unroll
        for (int ni = 0; ni < 4; ++ni)
#pragma unroll
            for (int r = 0; r < 4; ++r) {
                int gm = m0 + wm + mi*16 + quad*4 + r;
                int gc = n0 + wn + ni*16 + lc;
                float val = acc[mi][ni][r] + bias[gc];
                int which = gc >> 10, h = (gc >> 6) & 15, hd = gc & 63;
                if (which == 0) val *= QSCALE_;       // pre-scale Q
                bf16 bv = (bf16)val;
                int b = gm >> 11, n = gm & 2047;
                size_t base = (size_t)((z*BB_ + b)*HEADS_ + h);
                if (which == 0)      qbuf[(base*NN_ + n)*HD_ + hd] = bv;
                else if (which == 1) kbuf[(base*NN_ + n)*HD_ + hd] = bv;
                else                 vbuf[(base*HD_ + hd)*NN_ + n] = bv;
            }
}

__global__ __launch_bounds__(256) void out_gemm_legacy(
    const bf16* __restrict__ obuf,
    const float* __restrict__ Wr, const float* __restrict__ Wi,
    const float* __restrict__ br, const float* __restrict__ bi,
    float* __restrict__ out)
{
    const int z = blockIdx.z;
    const bf16*  __restrict__ A    = obuf + (size_t)z * MTOT_ * DIM_;
    const float* __restrict__ W    = z ? Wi : Wr;
    const float* __restrict__ bias = z ? bi : br;
    float* __restrict__ dst        = out + (size_t)z * MTOT_ * DIM_;
    const int n0 = blockIdx.x * 128;
    const int m0 = blockIdx.y * 128;

    __shared__ bf16 As[128*40];
    __shared__ bf16 Bs[128*40];

    const int tid  = threadIdx.x;
    const int w    = tid >> 6, lane = tid & 63;
    const int quad = lane >> 4, lc = lane & 15;
    const int wm   = (w >> 1) * 64, wn = (w & 1) * 64;

    const fx4 fzero = {0.f, 0.f, 0.f, 0.f};
    fx4 acc[4][4];
#pragma unroll
    for (int mi = 0; mi < 4; ++mi)
#pragma unroll
        for (int ni = 0; ni < 4; ++ni) acc[mi][ni] = fzero;

    for (int k0 = 0; k0 < DIM_; k0 += 32) {
#pragma unroll
        for (int it = 0; it < 2; ++it) {
            int flat = it*2048 + tid*8;
            int row = flat >> 5, col = flat & 31;
            *(bf16x8*)&As[row*40 + col] = *(const bf16x8*)(A + (size_t)(m0+row)*DIM_ + k0 + col);
            const float* pb = W + (size_t)(n0+row)*DIM_ + k0 + col;
            fx4 b0 = *(const fx4*)pb, b1 = *(const fx4*)(pb+4);
            bf16x8 bv;
#pragma unroll
            for (int j = 0; j < 4; ++j) { bv[j] = (bf16)b0[j]; bv[j+4] = (bf16)b1[j]; }
            *(bf16x8*)&Bs[row*40 + col] = bv;
        }
        __syncthreads();

        bf16x8 af[4], bfr[4];
#pragma unroll
        for (int mi = 0; mi < 4; ++mi) af[mi]  = *(bf16x8*)&As[(wm + mi*16 + lc)*40 + quad*8];
#pragma unroll
        for (int ni = 0; ni < 4; ++ni) bfr[ni] = *(bf16x8*)&Bs[(wn + ni*16 + lc)*40 + quad*8];
#pragma unroll
        for (int mi = 0; mi < 4; ++mi)
#pragma unroll
            for (int ni = 0; ni < 4; ++ni)
                acc[mi][ni] = __builtin_amdgcn_mfma_f32_16x16x32_bf16(af[mi], bfr[ni], acc[mi][ni], 0, 0, 0);
        __syncthreads();
    }

#pragma unroll
    for (int mi = 0; mi < 4; ++mi)
#pragma unroll
        for (int ni = 0; ni < 4; ++ni)
#pragma unroll
            for (int r = 0; r < 4; ++r) {
                int gm = m0 + wm + mi*16 + quad*4 + r;
                int gc = n0 + wn + ni*16 + lc;
                dst[(size_t)gm*DIM_ + gc] = acc[mi][ni][r] + bias[gc];
            }
}

// ---------------------------------------------------------------------------
extern "C" void kernel_launch(void* const* d_in, const int* in_sizes, int n_in,
                              void* d_out, int out_size, void* d_ws, size_t ws_size,
                              hipStream_t stream) {
    const float* xr  = (const float*)d_in[0];
    const float* xi  = (const float*)d_in[1];
    const float* Wqr = (const float*)d_in[2];
    const float* bqr = (const float*)d_in[3];
    const float* Wqi = (const float*)d_in[4];
    const float* bqi = (const float*)d_in[5];
    const float* Wor = (const float*)d_in[6];
    const float* bor = (const float*)d_in[7];
    const float* Woi = (const float*)d_in[8];
    const float* boi = (const float*)d_in[9];
    float* out = (float*)d_out;

    bf16* ws = (bf16*)d_ws;
    const size_t NEED = 83886080ull;

    if (ws_size >= NEED) {
        bf16* xbf  = ws;               // reused as obuf after qkv
        bf16* wqkv = ws + 8388608;
        bf16* wout = ws + 14680064;
        bf16* qb   = ws + 16777216;
        bf16* kb   = ws + 25165824;
        bf16* vb   = ws + 33554432;
        bf16* obuf = xbf;

        cvt_prepass<<<dim3(8192), 256, 0, stream>>>(xr, xi, Wqr, Wqi, Wor, Woi,
                                                    xbf, wqkv, wout);
        qkv_gemm_dma<<<dim3(24, 32, 2), 256, 0, stream>>>(xbf, wqkv, bqr, bqi,
                                                          qb, kb, vb);
        attn_fwd<<<dim3(512), 512, 0, stream>>>(qb, kb, vb, obuf);
        out_gemm_dma<<<dim3(8, 32, 2), 256, 0, stream>>>(obuf, wout, bor, boi, out);
    } else {
        const size_t per = (size_t)2 * BB_ * HEADS_ * NN_ * HD_;
        bf16* qb   = ws;
        bf16* kb   = ws + per;
        bf16* vb   = ws + 2*per;
        bf16* obuf = ws + 3*per;
        qkv_gemm_legacy<<<dim3(24, 32, 2), 256, 0, stream>>>(xr, xi, Wqr, Wqi,
                                                             bqr, bqi, qb, kb, vb);
        attn_fwd<<<dim3(512), 512, 0, stream>>>(qb, kb, vb, obuf);
        out_gemm_legacy<<<dim3(8, 32, 2), 256, 0, stream>>>(obuf, Wor, Woi,
                                                            bor, boi, out);
    }
}